// Round 1
// baseline (85.036 us; speedup 1.0000x reference)
//
#include <hip/hip_runtime.h>
#include <stdint.h>

typedef __attribute__((ext_vector_type(8))) __bf16 bf16x8;
typedef __attribute__((ext_vector_type(4))) float f32x4;

__device__ __forceinline__ unsigned short f2bf(float f) {
  union { float f; unsigned int u; } v; v.f = f;
  unsigned int u = v.u;
  return (unsigned short)((u + 0x7fffu + ((u >> 16) & 1u)) >> 16);
}

__device__ __forceinline__ void async_copy16(const void* g, void* s) {
  __builtin_amdgcn_global_load_lds(
      (__attribute__((address_space(1))) void*)const_cast<void*>(g),
      (__attribute__((address_space(3))) void*)s,
      16, 0, 0);
}

#define HAAR(a, bb, cc, dd, oA, oH, oV, oD)                                    \
  oA = 0.5f * ((a + bb) + (cc + dd));                                          \
  oH = 0.5f * ((a + bb) - (cc + dd));                                          \
  oV = 0.5f * ((a - bb) + (cc - dd));                                          \
  oD = 0.5f * ((a - bb) - (cc - dd));

// ---------------- W fp32 -> bf16 (already [N=768][K=768] row-major) --------
__global__ __launch_bounds__(256) void convw_kernel(const float* __restrict__ W,
                                                    unsigned short* __restrict__ Wb) {
  int i = blockIdx.x * 256 + threadIdx.x;  // 147456 threads x 4 floats
  float4 v = ((const float4*)W)[i];
  uint2 o;
  o.x = (unsigned int)f2bf(v.x) | ((unsigned int)f2bf(v.y) << 16);
  o.y = (unsigned int)f2bf(v.z) | ((unsigned int)f2bf(v.w) << 16);
  ((uint2*)Wb)[i] = o;
}

// ------- 2-level Haar DWT -> bf16 A[M=25088][K=768] in patch layout --------
// One thread per 4x4 input block: emits 12 level-1 detail coeffs + 4 level-2
// coeffs, scattered into A via the coeffs_to_array 224x224 layout:
//   [ [cA2|cH2; cV2|cD2] | cH1 ]
//   [      cV1           | cD1 ]
__global__ __launch_bounds__(256) void dwt2_kernel(const float* __restrict__ x,
                                                   unsigned short* __restrict__ A) {
  int tid = blockIdx.x * 256 + threadIdx.x;  // 128*3*56*56 = 1204224
  int J = tid % 56;
  int t = tid / 56;
  int I = t % 56;
  t /= 56;  // t = b*3 + c
  int c = t % 3;
  int b = t / 3;

  const float* xp = x + (((size_t)t * 224 + 4 * I) * 224 + 4 * J);
  float4 r0 = *(const float4*)(xp);
  float4 r1 = *(const float4*)(xp + 224);
  float4 r2 = *(const float4*)(xp + 448);
  float4 r3 = *(const float4*)(xp + 672);

  float A1[2][2], H1[2][2], V1[2][2], D1[2][2];
  HAAR(r0.x, r0.y, r1.x, r1.y, A1[0][0], H1[0][0], V1[0][0], D1[0][0]);
  HAAR(r0.z, r0.w, r1.z, r1.w, A1[0][1], H1[0][1], V1[0][1], D1[0][1]);
  HAAR(r2.x, r2.y, r3.x, r3.y, A1[1][0], H1[1][0], V1[1][0], D1[1][0]);
  HAAR(r2.z, r2.w, r3.z, r3.w, A1[1][1], H1[1][1], V1[1][1], D1[1][1]);

  auto aidx = [&](int y, int xx) -> size_t {
    int mrow = b * 196 + (y >> 4) * 14 + (xx >> 4);
    int k = c * 256 + (y & 15) * 16 + (xx & 15);
    return (size_t)mrow * 768 + (size_t)k;
  };
  auto store2 = [&](int y, int xx, float v0, float v1) {
    unsigned int p = (unsigned int)f2bf(v0) | ((unsigned int)f2bf(v1) << 16);
    *(unsigned int*)(A + aidx(y, xx)) = p;  // xx even -> 4B aligned, same patch
  };

  int y0 = 2 * I, x0 = 2 * J;
  store2(y0,           112 + x0, H1[0][0], H1[0][1]);
  store2(y0 + 1,       112 + x0, H1[1][0], H1[1][1]);
  store2(112 + y0,     x0,       V1[0][0], V1[0][1]);
  store2(112 + y0 + 1, x0,       V1[1][0], V1[1][1]);
  store2(112 + y0,     112 + x0, D1[0][0], D1[0][1]);
  store2(112 + y0 + 1, 112 + x0, D1[1][0], D1[1][1]);

  float vA2, vH2, vV2, vD2;
  HAAR(A1[0][0], A1[0][1], A1[1][0], A1[1][1], vA2, vH2, vV2, vD2);
  A[aidx(I,      J)]      = f2bf(vA2);
  A[aidx(I,      56 + J)] = f2bf(vH2);
  A[aidx(56 + I, J)]      = f2bf(vV2);
  A[aidx(56 + I, 56 + J)] = f2bf(vD2);
}

// --------- bf16 MFMA GEMM: C[M][N] = A[M][K] * Bt[N][K]^T + bias -----------
// M=25088, N=768, K=768. 128x128 tile, BK=32, 4 waves (64x64 each),
// 16x16x32 MFMA, global_load_lds(16B) staging, fp32 output = d_out layout.
__global__ __launch_bounds__(256) void gemm_kernel(const unsigned short* __restrict__ A,
                                                   const unsigned short* __restrict__ Bt,
                                                   const float* __restrict__ bias,
                                                   float* __restrict__ C) {
  constexpr int K = 768, N = 768;
  __shared__ unsigned short As[128 * 32];
  __shared__ unsigned short Bs[128 * 32];

  const int bn = blockIdx.x;  // 0..5
  const int bm = blockIdx.y;  // 0..195
  const int tid = threadIdx.x;
  const int lane = tid & 63;
  const int wave = tid >> 6;
  const int wr = wave >> 1, wc = wave & 1;
  const int mbase = bm * 128, nbase = bn * 128;

  f32x4 acc[4][4] = {};

  // staging: inst i covers LDS bytes [i*4096 + wave*1024, +1024), lane +16B
  const int off0 = wave * 1024 + lane * 16;
  const int row0 = off0 >> 6;         // 0..63
  const int kc0 = (off0 >> 4) & 3;    // k-chunk (8 bf16 = 16B)
  const unsigned short* ga0 = A + (size_t)(mbase + row0) * K + kc0 * 8;
  const unsigned short* ga1 = ga0 + (size_t)64 * K;
  const unsigned short* gb0 = Bt + (size_t)(nbase + row0) * K + kc0 * 8;
  const unsigned short* gb1 = gb0 + (size_t)64 * K;
  char* sa0 = (char*)As + wave * 1024;
  char* sb0 = (char*)Bs + wave * 1024;

  const int fr = lane & 15;   // fragment row (A row / Bt row = C col)
  const int kq = lane >> 4;   // k-quarter
  const unsigned short* pa = As + (wr * 64 + fr) * 32 + kq * 8;
  const unsigned short* pb = Bs + (wc * 64 + fr) * 32 + kq * 8;

  for (int kt = 0; kt < K; kt += 32) {
    __syncthreads();  // previous compute done reading LDS
    async_copy16(ga0 + kt, sa0);
    async_copy16(ga1 + kt, sa0 + 4096);
    async_copy16(gb0 + kt, sb0);
    async_copy16(gb1 + kt, sb0 + 4096);
    __syncthreads();  // staging drained (vmcnt(0) before barrier)

    bf16x8 af[4], bfv[4];
#pragma unroll
    for (int mi = 0; mi < 4; ++mi) af[mi] = *(const bf16x8*)(pa + mi * 16 * 32);
#pragma unroll
    for (int ni = 0; ni < 4; ++ni) bfv[ni] = *(const bf16x8*)(pb + ni * 16 * 32);
#pragma unroll
    for (int mi = 0; mi < 4; ++mi)
#pragma unroll
      for (int ni = 0; ni < 4; ++ni)
        acc[mi][ni] = __builtin_amdgcn_mfma_f32_16x16x32_bf16(af[mi], bfv[ni],
                                                              acc[mi][ni], 0, 0, 0);
  }

  // epilogue: C col = lane&15, row = (lane>>4)*4 + j ; fuse bias
  const int rq = lane >> 4;
#pragma unroll
  for (int ni = 0; ni < 4; ++ni) {
    int n = nbase + wc * 64 + ni * 16 + fr;
    float bv = bias[n];
#pragma unroll
    for (int mi = 0; mi < 4; ++mi) {
      int mrow = mbase + wr * 64 + mi * 16 + rq * 4;
      f32x4 v = acc[mi][ni];
#pragma unroll
      for (int j = 0; j < 4; ++j) C[(size_t)(mrow + j) * N + n] = v[j] + bv;
    }
  }
}

extern "C" void kernel_launch(void* const* d_in, const int* in_sizes, int n_in,
                              void* d_out, int out_size, void* d_ws, size_t ws_size,
                              hipStream_t stream) {
  const float* x = (const float*)d_in[0];     // (128,3,224,224) f32
  const float* W = (const float*)d_in[1];     // (768,3,16,16)  f32
  const float* bias = (const float*)d_in[2];  // (768,)         f32
  float* out = (float*)d_out;                 // (128,196,768)  f32

  unsigned short* A = (unsigned short*)d_ws;                        // 25088*768 bf16
  unsigned short* Wb = (unsigned short*)((char*)d_ws + 38535168);   // 589824 bf16

  convw_kernel<<<576, 256, 0, stream>>>(W, Wb);
  dwt2_kernel<<<4704, 256, 0, stream>>>(x, A);
  dim3 grid(6, 196);
  gemm_kernel<<<grid, 256, 0, stream>>>(A, Wb, bias, out);
}

// Round 2
// 75.410 us; speedup vs baseline: 1.1276x; 1.1276x over previous
//
#include <hip/hip_runtime.h>
#include <stdint.h>

typedef __attribute__((ext_vector_type(8))) __bf16 bf16x8;
typedef __attribute__((ext_vector_type(4))) float f32x4;

__device__ __forceinline__ unsigned short f2bf(float f) {
  union { float f; unsigned int u; } v; v.f = f;
  unsigned int u = v.u;
  return (unsigned short)((u + 0x7fffu + ((u >> 16) & 1u)) >> 16);
}

__device__ __forceinline__ void async_copy16(const void* g, void* s) {
  __builtin_amdgcn_global_load_lds(
      (__attribute__((address_space(1))) void*)const_cast<void*>(g),
      (__attribute__((address_space(3))) void*)s,
      16, 0, 0);
}

#define HAAR(a, bb, cc, dd, oA, oH, oV, oD)                                    \
  oA = 0.5f * ((a + bb) + (cc + dd));                                          \
  oH = 0.5f * ((a + bb) - (cc + dd));                                          \
  oV = 0.5f * ((a - bb) + (cc - dd));                                          \
  oD = 0.5f * ((a - bb) - (cc - dd));

// ---------------- W fp32 -> bf16 (already [N=768][K=768] row-major) --------
__global__ __launch_bounds__(256) void convw_kernel(const float* __restrict__ W,
                                                    unsigned short* __restrict__ Wb) {
  int i = blockIdx.x * 256 + threadIdx.x;  // 147456 threads x 4 floats
  float4 v = ((const float4*)W)[i];
  uint2 o;
  o.x = (unsigned int)f2bf(v.x) | ((unsigned int)f2bf(v.y) << 16);
  o.y = (unsigned int)f2bf(v.z) | ((unsigned int)f2bf(v.w) << 16);
  ((uint2*)Wb)[i] = o;
}

// ------- 2-level Haar DWT -> bf16 A[M=25088][K=768] in patch layout --------
__global__ __launch_bounds__(256) void dwt2_kernel(const float* __restrict__ x,
                                                   unsigned short* __restrict__ A) {
  int tid = blockIdx.x * 256 + threadIdx.x;  // 128*3*56*56 = 1204224
  int J = tid % 56;
  int t = tid / 56;
  int I = t % 56;
  t /= 56;  // t = b*3 + c
  int c = t % 3;
  int b = t / 3;

  const float* xp = x + (((size_t)t * 224 + 4 * I) * 224 + 4 * J);
  float4 r0 = *(const float4*)(xp);
  float4 r1 = *(const float4*)(xp + 224);
  float4 r2 = *(const float4*)(xp + 448);
  float4 r3 = *(const float4*)(xp + 672);

  float A1[2][2], H1[2][2], V1[2][2], D1[2][2];
  HAAR(r0.x, r0.y, r1.x, r1.y, A1[0][0], H1[0][0], V1[0][0], D1[0][0]);
  HAAR(r0.z, r0.w, r1.z, r1.w, A1[0][1], H1[0][1], V1[0][1], D1[0][1]);
  HAAR(r2.x, r2.y, r3.x, r3.y, A1[1][0], H1[1][0], V1[1][0], D1[1][0]);
  HAAR(r2.z, r2.w, r3.z, r3.w, A1[1][1], H1[1][1], V1[1][1], D1[1][1]);

  auto aidx = [&](int y, int xx) -> size_t {
    int mrow = b * 196 + (y >> 4) * 14 + (xx >> 4);
    int k = c * 256 + (y & 15) * 16 + (xx & 15);
    return (size_t)mrow * 768 + (size_t)k;
  };
  auto store2 = [&](int y, int xx, float v0, float v1) {
    unsigned int p = (unsigned int)f2bf(v0) | ((unsigned int)f2bf(v1) << 16);
    *(unsigned int*)(A + aidx(y, xx)) = p;  // xx even -> 4B aligned, same patch
  };

  int y0 = 2 * I, x0 = 2 * J;
  store2(y0,           112 + x0, H1[0][0], H1[0][1]);
  store2(y0 + 1,       112 + x0, H1[1][0], H1[1][1]);
  store2(112 + y0,     x0,       V1[0][0], V1[0][1]);
  store2(112 + y0 + 1, x0,       V1[1][0], V1[1][1]);
  store2(112 + y0,     112 + x0, D1[0][0], D1[0][1]);
  store2(112 + y0 + 1, 112 + x0, D1[1][0], D1[1][1]);

  float vA2, vH2, vV2, vD2;
  HAAR(A1[0][0], A1[0][1], A1[1][0], A1[1][1], vA2, vH2, vV2, vD2);
  A[aidx(I,      J)]      = f2bf(vA2);
  A[aidx(I,      56 + J)] = f2bf(vH2);
  A[aidx(56 + I, J)]      = f2bf(vV2);
  A[aidx(56 + I, 56 + J)] = f2bf(vD2);
}

// --------- bf16 MFMA GEMM: C[M][N] = A[M][K] * Bt[N][K]^T + bias -----------
// M=25088, N=768, K=768. 128x128 tile, BK=32, 4 waves (64x64 each).
// Double-buffered LDS, prefetch-1 (T3-minimum 2-phase), XCD-chunked swizzle.
__global__ __launch_bounds__(256) void gemm_kernel(const unsigned short* __restrict__ A,
                                                   const unsigned short* __restrict__ Bt,
                                                   const float* __restrict__ bias,
                                                   float* __restrict__ C) {
  constexpr int K = 768, N = 768;
  constexpr int NT = 24;  // K / 32
  __shared__ unsigned short As[2][128 * 32];  // 8 KB per buffer
  __shared__ unsigned short Bs[2][128 * 32];

  // XCD swizzle: 1176 tiles = 8 XCDs x 147 consecutive tiles (bijective).
  const int orig = blockIdx.x;
  const int tile = (orig & 7) * 147 + (orig >> 3);
  const int bm = tile / 6, bn = tile % 6;

  const int tid = threadIdx.x;
  const int lane = tid & 63;
  const int wave = tid >> 6;
  const int wr = wave >> 1, wc = wave & 1;
  const int mbase = bm * 128, nbase = bn * 128;

  f32x4 acc[4][4] = {};

  // staging: per buffer, inst i covers LDS bytes [i*4096 + wave*1024, +1024)
  const int off0 = wave * 1024 + lane * 16;
  const int row0 = off0 >> 6;         // 0..63
  const int kc0 = (off0 >> 4) & 3;    // k-chunk (8 bf16 = 16B)
  const unsigned short* ga0 = A + (size_t)(mbase + row0) * K + kc0 * 8;
  const unsigned short* ga1 = ga0 + (size_t)64 * K;
  const unsigned short* gb0 = Bt + (size_t)(nbase + row0) * K + kc0 * 8;
  const unsigned short* gb1 = gb0 + (size_t)64 * K;

  auto stage = [&](int buf, int kt) {
    char* sa = (char*)As + buf * 8192 + wave * 1024;
    char* sb = (char*)Bs + buf * 8192 + wave * 1024;
    const int ko = kt * 32;
    async_copy16(ga0 + ko, sa);
    async_copy16(ga1 + ko, sa + 4096);
    async_copy16(gb0 + ko, sb);
    async_copy16(gb1 + ko, sb + 4096);
  };

  const int fr = lane & 15;   // fragment row (A row / Bt row = C col)
  const int kq = lane >> 4;   // k-quarter

  stage(0, 0);
  asm volatile("s_waitcnt vmcnt(0)" ::: "memory");
  __syncthreads();

  for (int kt = 0; kt < NT; ++kt) {
    const int cur = kt & 1;
    if (kt < NT - 1) stage(cur ^ 1, kt + 1);  // prefetch next K-tile

    const unsigned short* pa = As[cur] + (wr * 64 + fr) * 32 + kq * 8;
    const unsigned short* pb = Bs[cur] + (wc * 64 + fr) * 32 + kq * 8;
    bf16x8 af[4], bv[4];
#pragma unroll
    for (int mi = 0; mi < 4; ++mi) af[mi] = *(const bf16x8*)(pa + mi * 16 * 32);
#pragma unroll
    for (int ni = 0; ni < 4; ++ni) bv[ni] = *(const bf16x8*)(pb + ni * 16 * 32);
#pragma unroll
    for (int mi = 0; mi < 4; ++mi)
#pragma unroll
      for (int ni = 0; ni < 4; ++ni)
        acc[mi][ni] = __builtin_amdgcn_mfma_f32_16x16x32_bf16(af[mi], bv[ni],
                                                              acc[mi][ni], 0, 0, 0);

    asm volatile("s_waitcnt vmcnt(0)" ::: "memory");  // next tile landed
    __syncthreads();  // all waves done reading buf[cur] & next tile visible
  }

  // epilogue: C col = lane&15, row = (lane>>4)*4 + j ; fuse bias
  const int rq = lane >> 4;
#pragma unroll
  for (int ni = 0; ni < 4; ++ni) {
    int n = nbase + wc * 64 + ni * 16 + fr;
    float bv = bias[n];
#pragma unroll
    for (int mi = 0; mi < 4; ++mi) {
      int mrow = mbase + wr * 64 + mi * 16 + rq * 4;
      f32x4 v = acc[mi][ni];
#pragma unroll
      for (int j = 0; j < 4; ++j) C[(size_t)(mrow + j) * N + n] = v[j] + bv;
    }
  }
}

extern "C" void kernel_launch(void* const* d_in, const int* in_sizes, int n_in,
                              void* d_out, int out_size, void* d_ws, size_t ws_size,
                              hipStream_t stream) {
  const float* x = (const float*)d_in[0];     // (128,3,224,224) f32
  const float* W = (const float*)d_in[1];     // (768,3,16,16)  f32
  const float* bias = (const float*)d_in[2];  // (768,)         f32
  float* out = (float*)d_out;                 // (128,196,768)  f32

  unsigned short* A = (unsigned short*)d_ws;                        // 25088*768 bf16
  unsigned short* Wb = (unsigned short*)((char*)d_ws + 38535168);   // 589824 bf16

  convw_kernel<<<576, 256, 0, stream>>>(W, Wb);
  dwt2_kernel<<<4704, 256, 0, stream>>>(x, A);
  gemm_kernel<<<1176, 256, 0, stream>>>(A, Wb, bias, out);
}

// Round 3
// 71.052 us; speedup vs baseline: 1.1968x; 1.0613x over previous
//
#include <hip/hip_runtime.h>
#include <stdint.h>

typedef __attribute__((ext_vector_type(8))) __bf16 bf16x8;
typedef __attribute__((ext_vector_type(4))) float f32x4;

__device__ __forceinline__ unsigned short f2bf(float f) {
  union { float f; unsigned int u; } v; v.f = f;
  unsigned int u = v.u;
  return (unsigned short)((u + 0x7fffu + ((u >> 16) & 1u)) >> 16);
}

__device__ __forceinline__ void async_copy16(const void* g, void* s) {
  __builtin_amdgcn_global_load_lds(
      (__attribute__((address_space(1))) void*)const_cast<void*>(g),
      (__attribute__((address_space(3))) void*)s,
      16, 0, 0);
}

#define HAAR(a, bb, cc, dd, oA, oH, oV, oD)                                    \
  oA = 0.5f * ((a + bb) + (cc + dd));                                          \
  oH = 0.5f * ((a + bb) - (cc + dd));                                          \
  oV = 0.5f * ((a - bb) + (cc - dd));                                          \
  oD = 0.5f * ((a - bb) - (cc - dd));

// ---------------- W fp32 -> bf16 (already [N=768][K=768] row-major) --------
__global__ __launch_bounds__(256) void convw_kernel(const float* __restrict__ W,
                                                    unsigned short* __restrict__ Wb) {
  int i = blockIdx.x * 256 + threadIdx.x;  // 147456 threads x 4 floats
  float4 v = ((const float4*)W)[i];
  uint2 o;
  o.x = (unsigned int)f2bf(v.x) | ((unsigned int)f2bf(v.y) << 16);
  o.y = (unsigned int)f2bf(v.z) | ((unsigned int)f2bf(v.w) << 16);
  ((uint2*)Wb)[i] = o;
}

// ------- 2-level Haar DWT -> bf16 A[M=25088][K=768] in patch layout --------
__global__ __launch_bounds__(256) void dwt2_kernel(const float* __restrict__ x,
                                                   unsigned short* __restrict__ A) {
  int tid = blockIdx.x * 256 + threadIdx.x;  // 128*3*56*56 = 1204224
  int J = tid % 56;
  int t = tid / 56;
  int I = t % 56;
  t /= 56;  // t = b*3 + c
  int c = t % 3;
  int b = t / 3;

  const float* xp = x + (((size_t)t * 224 + 4 * I) * 224 + 4 * J);
  float4 r0 = *(const float4*)(xp);
  float4 r1 = *(const float4*)(xp + 224);
  float4 r2 = *(const float4*)(xp + 448);
  float4 r3 = *(const float4*)(xp + 672);

  float A1[2][2], H1[2][2], V1[2][2], D1[2][2];
  HAAR(r0.x, r0.y, r1.x, r1.y, A1[0][0], H1[0][0], V1[0][0], D1[0][0]);
  HAAR(r0.z, r0.w, r1.z, r1.w, A1[0][1], H1[0][1], V1[0][1], D1[0][1]);
  HAAR(r2.x, r2.y, r3.x, r3.y, A1[1][0], H1[1][0], V1[1][0], D1[1][0]);
  HAAR(r2.z, r2.w, r3.z, r3.w, A1[1][1], H1[1][1], V1[1][1], D1[1][1]);

  auto aidx = [&](int y, int xx) -> size_t {
    int mrow = b * 196 + (y >> 4) * 14 + (xx >> 4);
    int k = c * 256 + (y & 15) * 16 + (xx & 15);
    return (size_t)mrow * 768 + (size_t)k;
  };
  auto store2 = [&](int y, int xx, float v0, float v1) {
    unsigned int p = (unsigned int)f2bf(v0) | ((unsigned int)f2bf(v1) << 16);
    *(unsigned int*)(A + aidx(y, xx)) = p;  // xx even -> 4B aligned, same patch
  };

  int y0 = 2 * I, x0 = 2 * J;
  store2(y0,           112 + x0, H1[0][0], H1[0][1]);
  store2(y0 + 1,       112 + x0, H1[1][0], H1[1][1]);
  store2(112 + y0,     x0,       V1[0][0], V1[0][1]);
  store2(112 + y0 + 1, x0,       V1[1][0], V1[1][1]);
  store2(112 + y0,     112 + x0, D1[0][0], D1[0][1]);
  store2(112 + y0 + 1, 112 + x0, D1[1][0], D1[1][1]);

  float vA2, vH2, vV2, vD2;
  HAAR(A1[0][0], A1[0][1], A1[1][0], A1[1][1], vA2, vH2, vV2, vD2);
  A[aidx(I,      J)]      = f2bf(vA2);
  A[aidx(I,      56 + J)] = f2bf(vH2);
  A[aidx(56 + I, J)]      = f2bf(vV2);
  A[aidx(56 + I, 56 + J)] = f2bf(vD2);
}

// --------- bf16 MFMA GEMM: C[M][N] = A[M][K] * Bt[N][K]^T + bias -----------
// M=25088, N=768, K=768. 128x128 tile, BK=32, 4 waves (64x64 each).
// Triple-buffered LDS, prefetch depth 2, counted vmcnt + raw s_barrier,
// chunk-XOR LDS swizzle (pre-swizzled global source, swizzled ds_read).
__global__ __launch_bounds__(256) void gemm_kernel(const unsigned short* __restrict__ A,
                                                   const unsigned short* __restrict__ Bt,
                                                   const float* __restrict__ bias,
                                                   float* __restrict__ C) {
  constexpr int K = 768, N = 768;
  constexpr int NT = 24;  // K / 32
  // 3 buffers x 8KB per operand; row = 64B (32 bf16), chunk = 16B
  __shared__ unsigned short As[3][128 * 32];
  __shared__ unsigned short Bs[3][128 * 32];

  // XCD swizzle: 1176 tiles = 8 XCDs x 147 consecutive tiles (bijective).
  const int orig = blockIdx.x;
  const int tile = (orig & 7) * 147 + (orig >> 3);
  const int bm = tile / 6, bn = tile % 6;

  const int tid = threadIdx.x;
  const int lane = tid & 63;
  const int wave = tid >> 6;
  const int wr = wave >> 1, wc = wave & 1;
  const int mbase = bm * 128, nbase = bn * 128;

  f32x4 acc[4][4] = {};

  // --- staging addresses (wave-uniform LDS base + lane*16 dest) ---
  // lane covers physical (row0, chunk kc0) of a 64-row half; source k-chunk
  // is pre-swizzled: logical chunk = kc0 ^ ((row0>>1)&3)  (involution).
  const int off0 = wave * 1024 + lane * 16;
  const int row0 = off0 >> 6;                    // 0..63
  const int kc0 = (off0 >> 4) & 3;
  const int kcs = kc0 ^ ((row0 >> 1) & 3);       // swizzled source chunk
  const unsigned short* ga0 = A + (size_t)(mbase + row0) * K + kcs * 8;
  const unsigned short* ga1 = ga0 + (size_t)64 * K;   // rows 64..127: same XOR
  const unsigned short* gb0 = Bt + (size_t)(nbase + row0) * K + kcs * 8;
  const unsigned short* gb1 = gb0 + (size_t)64 * K;

  auto stage = [&](int buf, int kt) {
    char* sa = (char*)As + buf * 8192 + wave * 1024;
    char* sb = (char*)Bs + buf * 8192 + wave * 1024;
    const int ko = kt * 32;
    async_copy16(ga0 + ko, sa);
    async_copy16(ga1 + ko, sa + 4096);
    async_copy16(gb0 + ko, sb);
    async_copy16(gb1 + ko, sb + 4096);
  };

  const int fr = lane & 15;   // fragment row (A row / Bt row = C col)
  const int kq = lane >> 4;   // k-quarter (16B chunk)
  const int chq = kq ^ ((fr >> 1) & 3);  // swizzled read chunk (uniform in mi)

  stage(0, 0);
  stage(1, 1);

#pragma unroll
  for (int kt = 0; kt < NT; ++kt) {
    if (kt < NT - 1)
      asm volatile("s_waitcnt vmcnt(4)" ::: "memory");  // tile kt landed
    else
      asm volatile("s_waitcnt vmcnt(0)" ::: "memory");
    __builtin_amdgcn_s_barrier();       // tile kt visible; prev reads done
    if (kt + 2 < NT) stage((kt + 2) % 3, kt + 2);

    const char* pa = (const char*)As + (kt % 3) * 8192 + (wr * 64 + fr) * 64 + chq * 16;
    const char* pb = (const char*)Bs + (kt % 3) * 8192 + (wc * 64 + fr) * 64 + chq * 16;
    bf16x8 af[4], bv[4];
#pragma unroll
    for (int mi = 0; mi < 4; ++mi) af[mi] = *(const bf16x8*)(pa + mi * 16 * 64);
#pragma unroll
    for (int ni = 0; ni < 4; ++ni) bv[ni] = *(const bf16x8*)(pb + ni * 16 * 64);
#pragma unroll
    for (int mi = 0; mi < 4; ++mi)
#pragma unroll
      for (int ni = 0; ni < 4; ++ni)
        acc[mi][ni] = __builtin_amdgcn_mfma_f32_16x16x32_bf16(af[mi], bv[ni],
                                                              acc[mi][ni], 0, 0, 0);
    asm volatile("s_waitcnt lgkmcnt(0)" ::: "memory");  // reads done pre-barrier
  }

  // epilogue: C col = lane&15, row = (lane>>4)*4 + j ; fuse bias
  const int rq = lane >> 4;
#pragma unroll
  for (int ni = 0; ni < 4; ++ni) {
    int n = nbase + wc * 64 + ni * 16 + fr;
    float bv = bias[n];
#pragma unroll
    for (int mi = 0; mi < 4; ++mi) {
      int mrow = mbase + wr * 64 + mi * 16 + rq * 4;
      f32x4 v = acc[mi][ni];
#pragma unroll
      for (int j = 0; j < 4; ++j) C[(size_t)(mrow + j) * N + n] = v[j] + bv;
    }
  }
}

extern "C" void kernel_launch(void* const* d_in, const int* in_sizes, int n_in,
                              void* d_out, int out_size, void* d_ws, size_t ws_size,
                              hipStream_t stream) {
  const float* x = (const float*)d_in[0];     // (128,3,224,224) f32
  const float* W = (const float*)d_in[1];     // (768,3,16,16)  f32
  const float* bias = (const float*)d_in[2];  // (768,)         f32
  float* out = (float*)d_out;                 // (128,196,768)  f32

  unsigned short* A = (unsigned short*)d_ws;                        // 25088*768 bf16
  unsigned short* Wb = (unsigned short*)((char*)d_ws + 38535168);   // 589824 bf16

  convw_kernel<<<576, 256, 0, stream>>>(W, Wb);
  dwt2_kernel<<<4704, 256, 0, stream>>>(x, A);
  gemm_kernel<<<1176, 256, 0, stream>>>(A, Wb, bias, out);
}